// Round 5
// baseline (2137.451 us; speedup 1.0000x reference)
//
#include <hip/hip_runtime.h>
#include <stdint.h>

#define NROWS 131072
#define NC 1024
#define ND 512
#define BM 64
#define NSTEP 32   // 16 K-steps x {hi, lo} B-tables

using f32x4   = __attribute__((ext_vector_type(4))) float;
using bf16x8  = __attribute__((ext_vector_type(8))) short;
using short4v = __attribute__((ext_vector_type(4))) short;
using float4v = __attribute__((ext_vector_type(4))) float;

__device__ __forceinline__ uint16_t f32_bf16(float f) {
  uint32_t u = __builtin_bit_cast(uint32_t, f);
  u += 0x7FFFu + ((u >> 16) & 1u);   // RNE
  return (uint16_t)(u >> 16);
}
__device__ __forceinline__ float bf16_f32(uint16_t h) {
  uint32_t u = ((uint32_t)h) << 16;
  return __builtin_bit_cast(float, u);
}

__device__ __forceinline__ void gload_lds16(const void* g, void* l) {
  __builtin_amdgcn_global_load_lds(
      (const __attribute__((address_space(1))) unsigned int*)g,
      (__attribute__((address_space(3))) unsigned int*)l, 16, 0, 0);
}

// ---------------------------------------------------------------------------
// Prep: split centers into bf16 hi/lo, pre-permuted so each 32-k slice is a
// contiguous 64KB block whose LINEAR copy into LDS yields the swizzled layout:
// LDS[c*64 + p*16 + b] holds logical 16B chunk j = p ^ ((c>>1)&3) of row c.
// ((c>>1)&3) spreads every 16-lane quarter-wave of a b128 read over all 8
// bank-quads (the (c&3) variant only hit 4 of 8 -> 2x conflict, round 4).
// Also computes csq[c] in fp32.
// ---------------------------------------------------------------------------
__global__ __launch_bounds__(64) void prep_centers(
    const float* __restrict__ centers,
    uint16_t* __restrict__ cs_hi, uint16_t* __restrict__ cs_lo,
    float* __restrict__ csq) {
  const int c = blockIdx.x;   // 1024
  const int t = threadIdx.x;  // 64
  const float* row = centers + (size_t)c * ND;
  const int k0 = t * 8;
  float v[8];
#pragma unroll
  for (int i = 0; i < 8; ++i) v[i] = row[k0 + i];
  float ss = 0.f;
#pragma unroll
  for (int i = 0; i < 8; ++i) ss += v[i] * v[i];
#pragma unroll
  for (int m = 1; m < 64; m <<= 1) ss += __shfl_xor(ss, m);
  if (t == 0) csq[c] = ss;

  const int kk = t >> 2;               // K-step 0..15
  const int j  = t & 3;                // logical 16B chunk within K-step
  const int p  = j ^ ((c >> 1) & 3);   // physical chunk (XOR swizzle)
  const size_t off = (size_t)kk * 32768 + (size_t)c * 32 + (size_t)p * 8;
#pragma unroll
  for (int i = 0; i < 8; ++i) {
    uint16_t h = f32_bf16(v[i]);
    uint16_t l = f32_bf16(v[i] - bf16_f32(h));
    cs_hi[off + i] = h;
    cs_lo[off + i] = l;
  }
}

// ---------------------------------------------------------------------------
// Fused kernel: 64 rows x full 1024 cols per block. 512 threads / 8 waves,
// wave tile 64x128 (acc[4][8] -> 128 AGPR). Double-buffered B (2x64KB) + A
// (2x4KB hi + 2x4KB lo) -> 147.7KB LDS, 1 block/CU, 2 waves/SIMD.
// 2-phase pipeline (T3 short form): stage(s+1) issued BEFORE compute(s);
// the vmcnt(0) drain at the barrier lands after ~2500cyc of MFMA.
// Pass H (s<16): B=cs_hi, acc += a_hi*b + a_lo*b  (xsq fused here)
// Pass L (s>=16): B=cs_lo, acc += a_hi*b
// Epilogue: LDS transpose + row-local softmax + contiguous float4 stores.
// ---------------------------------------------------------------------------
__global__ __launch_bounds__(512)
__attribute__((amdgpu_waves_per_eu(2)))
void kmeans_fused(
    const float* __restrict__ x,
    const uint16_t* __restrict__ cs_hi, const uint16_t* __restrict__ cs_lo,
    const float* __restrict__ csq,
    float* __restrict__ dist, float* __restrict__ prob) {
  __shared__ __align__(16) char bs[2][65536];    // 1024 cols x 32 bf16, swizzled
  __shared__ __align__(16) char as_hi[2][4096];  // 64 rows x 32 bf16, swizzled
  __shared__ __align__(16) char as_lo[2][4096];
  __shared__ float xsq[BM];

  const int tid  = threadIdx.x;
  const int lane = tid & 63;
  const int wid  = tid >> 6;   // 0..7 -> cols wid*128
  const int row0 = blockIdx.x * BM;
  const int ar = tid >> 3;     // staging row 0..63
  const int ac = tid & 7;      // staging col-chunk (4 floats each)

  auto stage = [&](int s) {
    const uint16_t* base = (s < 16) ? cs_hi : cs_lo;
    const char* srcb = (const char*)(base + (size_t)(s & 15) * 32768);
    char* dst = bs[s & 1];
#pragma unroll
    for (int i = 0; i < 8; ++i) {
      const int o = (tid + i * 512) * 16;
      gload_lds16(srcb + o, dst + o);
    }
  };
  auto xload = [&](int s) -> float4v {
    return *(const float4v*)(x + (size_t)(row0 + ar) * ND + (s & 15) * 32 + ac * 4);
  };
  auto awrite = [&](int s, float4v v) {
    const int j = ac >> 1;                  // logical 16B chunk
    const int p = j ^ ((ar >> 1) & 3);      // physical chunk
    const int off = ar * 64 + p * 16 + (ac & 1) * 8;
    short4v h, l;
#pragma unroll
    for (int i = 0; i < 4; ++i) {
      uint16_t hb = f32_bf16(v[i]);
      h[i] = (short)hb;
      l[i] = (short)f32_bf16(v[i] - bf16_f32(hb));
    }
    *(short4v*)(as_hi[s & 1] + off) = h;
    *(short4v*)(as_lo[s & 1] + off) = l;
  };

  f32x4 acc[4][8];
  const f32x4 z = {0.f, 0.f, 0.f, 0.f};
#pragma unroll
  for (int mr = 0; mr < 4; ++mr)
#pragma unroll
    for (int n = 0; n < 8; ++n) acc[mr][n] = z;

  // fragment LDS byte offsets; row of frag = base + (lane&15), bases are
  // multiples of 16 so (row>>1)&3 == ((lane&15)>>1)&3
  const int swz  = (((lane >> 4) ^ (((lane & 15) >> 1) & 3)) << 4);
  const int aoff = (lane & 15) * 64 + swz;                // + mr*1024
  const int boff = (wid * 128 + (lane & 15)) * 64 + swz;  // + n*1024

  auto compute = [&](int s) {
    const char* bp  = bs[s & 1];
    const char* ahp = as_hi[s & 1];
    bf16x8 ah[4];
#pragma unroll
    for (int mr = 0; mr < 4; ++mr)
      ah[mr] = *(const bf16x8*)(ahp + aoff + mr * 1024);
    if (s < 16) {
      const char* alp = as_lo[s & 1];
      bf16x8 al[4];
#pragma unroll
      for (int mr = 0; mr < 4; ++mr)
        al[mr] = *(const bf16x8*)(alp + aoff + mr * 1024);
#pragma unroll
      for (int n = 0; n < 8; ++n) {
        bf16x8 b = *(const bf16x8*)(bp + boff + n * 1024);
#pragma unroll
        for (int mr = 0; mr < 4; ++mr)
          acc[mr][n] = __builtin_amdgcn_mfma_f32_16x16x32_bf16(ah[mr], b, acc[mr][n], 0, 0, 0);
#pragma unroll
        for (int mr = 0; mr < 4; ++mr)
          acc[mr][n] = __builtin_amdgcn_mfma_f32_16x16x32_bf16(al[mr], b, acc[mr][n], 0, 0, 0);
      }
    } else {
#pragma unroll
      for (int n = 0; n < 8; ++n) {
        bf16x8 b = *(const bf16x8*)(bp + boff + n * 1024);
#pragma unroll
        for (int mr = 0; mr < 4; ++mr)
          acc[mr][n] = __builtin_amdgcn_mfma_f32_16x16x32_bf16(ah[mr], b, acc[mr][n], 0, 0, 0);
      }
    }
  };

  float xacc = 0.f;

  // ---- prologue ----
  stage(0);
  {
    float4v v0 = xload(0);
    xacc += v0[0] * v0[0] + v0[1] * v0[1] + v0[2] * v0[2] + v0[3] * v0[3];
    awrite(0, v0);
  }
  __syncthreads();

  // ---- main loop: prefetch(s+1) || compute(s) ----
#pragma unroll 1
  for (int s = 0; s < NSTEP; ++s) {
    if (s + 1 < NSTEP) {
      float4v vn = xload(s + 1);
      stage(s + 1);
      if (s + 1 < 16)
        xacc += vn[0] * vn[0] + vn[1] * vn[1] + vn[2] * vn[2] + vn[3] * vn[3];
      compute(s);
      awrite(s + 1, vn);
    } else {
      compute(s);
    }
    __syncthreads();
  }

  // ---- xsq finalize: reduce over the 8 threads sharing row ar ----
  xacc += __shfl_xor(xacc, 1);
  xacc += __shfl_xor(xacc, 2);
  xacc += __shfl_xor(xacc, 4);
  if (ac == 0) xsq[ar] = xacc;

  // ---- epilogue: LDS transpose (16 rows/pass) + row-local softmax ----
  float* ldsT = (float*)bs;   // 16 x 1024 fp32 = 64KB (bs[0] half)
  const int rsub = (lane >> 4) * 4;
#pragma unroll
  for (int p = 0; p < 4; ++p) {
#pragma unroll
    for (int n = 0; n < 8; ++n)
#pragma unroll
      for (int r = 0; r < 4; ++r) {
        const int lrow = rsub + r;
        const int col = wid * 128 + n * 16 + (lane & 15);
        ldsT[lrow * 1024 + (col ^ (((lrow >> 2) & 3) << 3))] = acc[p][n][r];
      }
    __syncthreads();
#pragma unroll
    for (int q = 0; q < 2; ++q) {
      const int lr = wid * 2 + q;          // one wave -> 2 rows per pass
      const size_t grow = (size_t)(row0 + p * 16 + lr);
      const int cmask = ((lr >> 2) & 3) << 3;
      const float xq = xsq[p * 16 + lr];
      float4v dd[4];
      float dmin = 1e30f;
#pragma unroll
      for (int j = 0; j < 4; ++j) {
        const int f = lane * 4 + j * 256;
        float4v raw = *(const float4v*)&ldsT[lr * 1024 + (f ^ cmask)];
        float4v cq = *(const float4v*)(csq + f);
#pragma unroll
        for (int i = 0; i < 4; ++i) {
          float d = fmaxf(xq + cq[i] - 2.0f * raw[i], 0.0f);
          dd[j][i] = d;
          dmin = fminf(dmin, d);
        }
      }
#pragma unroll
      for (int m = 1; m < 64; m <<= 1) dmin = fminf(dmin, __shfl_xor(dmin, m));
#pragma unroll
      for (int j = 0; j < 4; ++j)
        *(float4v*)(dist + grow * NC + lane * 4 + j * 256) = dd[j];
      float ssum = 0.f;
#pragma unroll
      for (int j = 0; j < 4; ++j)
#pragma unroll
        for (int i = 0; i < 4; ++i) {
          float e = __expf(dmin - dd[j][i]);
          dd[j][i] = e;
          ssum += e;
        }
#pragma unroll
      for (int m = 1; m < 64; m <<= 1) ssum += __shfl_xor(ssum, m);
      const float sinv = 1.0f / ssum;
#pragma unroll
      for (int j = 0; j < 4; ++j) {
        float4v pv;
#pragma unroll
        for (int i = 0; i < 4; ++i) pv[i] = dd[j][i] * sinv;
        *(float4v*)(prob + grow * NC + lane * 4 + j * 256) = pv;
      }
    }
    __syncthreads();
  }
}

extern "C" void kernel_launch(void* const* d_in, const int* in_sizes, int n_in,
                              void* d_out, int out_size, void* d_ws, size_t ws_size,
                              hipStream_t stream) {
  const float* x = (const float*)d_in[0];
  const float* centers = (const float*)d_in[1];
  float* dist = (float*)d_out;
  float* prob = dist + (size_t)NROWS * NC;

  uint16_t* cs_hi = (uint16_t*)d_ws;                 // 1 MB
  uint16_t* cs_lo = cs_hi + (size_t)NC * ND;         // 1 MB
  float* csq = (float*)(cs_lo + (size_t)NC * ND);    // 4 KB

  prep_centers<<<dim3(NC), dim3(64), 0, stream>>>(centers, cs_hi, cs_lo, csq);
  kmeans_fused<<<dim3(NROWS / BM), dim3(512), 0, stream>>>(x, cs_hi, cs_lo, csq,
                                                           dist, prob);
}

// Round 6
// 1157.685 us; speedup vs baseline: 1.8463x; 1.8463x over previous
//
#include <hip/hip_runtime.h>
#include <stdint.h>

#define NROWS 131072
#define NC 1024
#define ND 512
#define BM 32
#define NSTEP 32   // 16 K-steps x {hi, lo} B-tables

using f32x4   = __attribute__((ext_vector_type(4))) float;
using bf16x8  = __attribute__((ext_vector_type(8))) short;
using float4v = __attribute__((ext_vector_type(4))) float;

#define WAITV12() asm volatile("s_waitcnt vmcnt(12)" ::: "memory")
#define WAITV0()  asm volatile("s_waitcnt vmcnt(0)" ::: "memory")

__device__ __forceinline__ uint16_t f32_bf16(float f) {
  uint32_t u = __builtin_bit_cast(uint32_t, f);
  u += 0x7FFFu + ((u >> 16) & 1u);   // RNE
  return (uint16_t)(u >> 16);
}
__device__ __forceinline__ float bf16_f32(uint16_t h) {
  uint32_t u = ((uint32_t)h) << 16;
  return __builtin_bit_cast(float, u);
}

__device__ __forceinline__ void gload_lds16(const void* g, void* l) {
  __builtin_amdgcn_global_load_lds(
      (const __attribute__((address_space(1))) unsigned int*)g,
      (__attribute__((address_space(3))) unsigned int*)l, 16, 0, 0);
}

// ---------------------------------------------------------------------------
// Prep: split centers into bf16 hi/lo, pre-permuted so each 32-k slice is a
// contiguous 64KB block whose LINEAR copy into LDS yields the swizzled layout:
// LDS[c*64 + p*16 + b] holds logical 16B chunk j = p ^ ((c>>1)&3) of row c.
// (proven round 5: bank conflicts 5.0e7 -> 4.2e6). Also computes csq[c].
// ---------------------------------------------------------------------------
__global__ __launch_bounds__(64) void prep_centers(
    const float* __restrict__ centers,
    uint16_t* __restrict__ cs_hi, uint16_t* __restrict__ cs_lo,
    float* __restrict__ csq) {
  const int c = blockIdx.x;   // 1024
  const int t = threadIdx.x;  // 64
  const float* row = centers + (size_t)c * ND;
  const int k0 = t * 8;
  float v[8];
#pragma unroll
  for (int i = 0; i < 8; ++i) v[i] = row[k0 + i];
  float ss = 0.f;
#pragma unroll
  for (int i = 0; i < 8; ++i) ss += v[i] * v[i];
#pragma unroll
  for (int m = 1; m < 64; m <<= 1) ss += __shfl_xor(ss, m);
  if (t == 0) csq[c] = ss;

  const int kk = t >> 2;               // K-step 0..15
  const int j  = t & 3;                // logical 16B chunk within K-step
  const int p  = j ^ ((c >> 1) & 3);   // physical chunk (XOR swizzle)
  const size_t off = (size_t)kk * 32768 + (size_t)c * 32 + (size_t)p * 8;
#pragma unroll
  for (int i = 0; i < 8; ++i) {
    uint16_t h = f32_bf16(v[i]);
    uint16_t l = f32_bf16(v[i] - bf16_f32(h));
    cs_hi[off + i] = h;
    cs_lo[off + i] = l;
  }
}

// ---------------------------------------------------------------------------
// Fused kernel: 32 rows x 1024 cols per block, 512 thr / 8 waves (32x128
// wave tile, acc[2][8] = 64 regs -> proven no-spill point). B double-buffered
// 2x64KB, staged via global_load_lds kept IN FLIGHT across raw s_barriers
// with counted vmcnt(12) (T3/T4). A loaded direct-to-reg from global (no LDS
// roundtrip), hi/lo split inline; xsq folded in. T5 setprio around MFMA.
// Epilogue: LDS transpose + row-wave softmax + contiguous float4 stores.
// ---------------------------------------------------------------------------
__global__ __launch_bounds__(512) void kmeans_fused(
    const float* __restrict__ x,
    const uint16_t* __restrict__ cs_hi, const uint16_t* __restrict__ cs_lo,
    const float* __restrict__ csq,
    float* __restrict__ dist, float* __restrict__ prob) {
  __shared__ __align__(16) char bs[2][65536];   // 1024 cols x 32 bf16, swizzled
  __shared__ float xsq[BM];

  const int tid  = threadIdx.x;
  const int lane = tid & 63;
  const int wid  = tid >> 6;        // 0..7 -> cols wid*128
  const int row0 = blockIdx.x * BM;
  const int arow = lane & 15;       // A fragment row (mr=0); mr=1 adds 16
  const int kq   = lane >> 4;       // k-quarter 0..3

  const float* xa0 = x + (size_t)(row0 + arow) * ND + kq * 8;
  const float* xa1 = xa0 + (size_t)16 * ND;

  auto stage = [&](int s) {
    const uint16_t* base = (s < 16) ? cs_hi : cs_lo;
    const char* srcb = (const char*)(base + (size_t)(s & 15) * 32768);
    char* dst = bs[s & 1];
    const int o = tid * 16;
#pragma unroll
    for (int i = 0; i < 8; ++i)
      gload_lds16(srcb + o + i * 8192, dst + o + i * 8192);
  };

  f32x4 acc[2][8];
  const f32x4 z = {0.f, 0.f, 0.f, 0.f};
#pragma unroll
  for (int mr = 0; mr < 2; ++mr)
#pragma unroll
    for (int n = 0; n < 8; ++n) acc[mr][n] = z;

  // B fragment LDS byte offset (col = wid*128 + arow + n*16; bases mult of 16
  // so (col>>1)&3 == (arow>>1)&3)
  const int swz  = ((kq ^ ((arow >> 1) & 3)) << 4);
  const int boff = (wid * 128 + arow) * 64 + swz;

  float xacc0 = 0.f, xacc1 = 0.f;

  // cvt batch -> frags (hi always; lo + xsq only for pass H)
  bf16x8 ah0, ah1, al0, al1;
  auto cvt = [&](int s, const float4v& a0a, const float4v& a0b,
                 const float4v& a1a, const float4v& a1b) {
    float v0[8] = {a0a[0], a0a[1], a0a[2], a0a[3], a0b[0], a0b[1], a0b[2], a0b[3]};
    float v1[8] = {a1a[0], a1a[1], a1a[2], a1a[3], a1b[0], a1b[1], a1b[2], a1b[3]};
#pragma unroll
    for (int i = 0; i < 8; ++i) {
      uint16_t h0 = f32_bf16(v0[i]);
      uint16_t h1 = f32_bf16(v1[i]);
      ah0[i] = (short)h0;
      ah1[i] = (short)h1;
    }
    if (s < 16) {
#pragma unroll
      for (int i = 0; i < 8; ++i) {
        al0[i] = (short)f32_bf16(v0[i] - bf16_f32((uint16_t)(unsigned short)ah0[i]));
        al1[i] = (short)f32_bf16(v1[i] - bf16_f32((uint16_t)(unsigned short)ah1[i]));
        xacc0 += v0[i] * v0[i];
        xacc1 += v1[i] * v1[i];
      }
    }
  };

  auto compute = [&](int s) {
    const char* bp = bs[s & 1];
    __builtin_amdgcn_s_setprio(1);
    if (s < 16) {
#pragma unroll
      for (int n = 0; n < 8; ++n) {
        bf16x8 b = *(const bf16x8*)(bp + boff + n * 1024);
        acc[0][n] = __builtin_amdgcn_mfma_f32_16x16x32_bf16(ah0, b, acc[0][n], 0, 0, 0);
        acc[1][n] = __builtin_amdgcn_mfma_f32_16x16x32_bf16(ah1, b, acc[1][n], 0, 0, 0);
        acc[0][n] = __builtin_amdgcn_mfma_f32_16x16x32_bf16(al0, b, acc[0][n], 0, 0, 0);
        acc[1][n] = __builtin_amdgcn_mfma_f32_16x16x32_bf16(al1, b, acc[1][n], 0, 0, 0);
      }
    } else {
#pragma unroll
      for (int n = 0; n < 8; ++n) {
        bf16x8 b = *(const bf16x8*)(bp + boff + n * 1024);
        acc[0][n] = __builtin_amdgcn_mfma_f32_16x16x32_bf16(ah0, b, acc[0][n], 0, 0, 0);
        acc[1][n] = __builtin_amdgcn_mfma_f32_16x16x32_bf16(ah1, b, acc[1][n], 0, 0, 0);
      }
    }
    __builtin_amdgcn_s_setprio(0);
  };

  // ---- prologue: batch 0 in flight (8 stage + 4 A loads = 12 vmem ops) ----
  float4v Ax0a, Ax0b, Ax1a, Ax1b;   // even-step A batch
  float4v Ay0a, Ay0b, Ay1a, Ay1b;   // odd-step A batch
  stage(0);
  {
    const float* p0 = xa0;
    const float* p1 = xa1;
    Ax0a = *(const float4v*)p0;       Ax0b = *(const float4v*)(p0 + 4);
    Ax1a = *(const float4v*)p1;       Ax1b = *(const float4v*)(p1 + 4);
  }

  // ---- main loop, unrolled x2 (static A ping-pong, rule #20) ----
#pragma unroll 1
  for (int s2 = 0; s2 < NSTEP; s2 += 2) {
    // even step s2: consume Ax, prefetch batch s2+1 -> Ay
    {
      const int sn = s2 + 1;
      stage(sn);
      const float* p0 = xa0 + (sn & 15) * 32;
      const float* p1 = xa1 + (sn & 15) * 32;
      Ay0a = *(const float4v*)p0;     Ay0b = *(const float4v*)(p0 + 4);
      Ay1a = *(const float4v*)p1;     Ay1b = *(const float4v*)(p1 + 4);
      WAITV12();                      // batch s2 (12 oldest) complete
      cvt(s2, Ax0a, Ax0b, Ax1a, Ax1b);
      __builtin_amdgcn_s_barrier();   // bs[s2&1] ready for all waves
      compute(s2);
      __builtin_amdgcn_s_barrier();   // reads done before overwrite
    }
    // odd step s2+1: consume Ay, prefetch batch s2+2 -> Ax
    {
      const int s = s2 + 1;
      const int sn = s2 + 2;
      if (sn < NSTEP) {
        stage(sn);
        const float* p0 = xa0 + (sn & 15) * 32;
        const float* p1 = xa1 + (sn & 15) * 32;
        Ax0a = *(const float4v*)p0;   Ax0b = *(const float4v*)(p0 + 4);
        Ax1a = *(const float4v*)p1;   Ax1b = *(const float4v*)(p1 + 4);
        WAITV12();
      } else {
        WAITV0();
      }
      cvt(s, Ay0a, Ay0b, Ay1a, Ay1b);
      __builtin_amdgcn_s_barrier();
      compute(s);
      __builtin_amdgcn_s_barrier();
    }
  }

  // ---- xsq: reduce k-quarters (lanes l, l+16, l+32, l+48 share a row) ----
  xacc0 += __shfl_xor(xacc0, 16);
  xacc0 += __shfl_xor(xacc0, 32);
  xacc1 += __shfl_xor(xacc1, 16);
  xacc1 += __shfl_xor(xacc1, 32);
  if (wid == 0 && lane < 16) {
    xsq[arow] = xacc0;
    xsq[arow + 16] = xacc1;
  }

  // ---- epilogue: LDS transpose (16 rows/pass) + row-wave softmax ----
  float* ldsT = (float*)bs;   // 16 x 1024 fp32 = 64KB
  const int rsub = (lane >> 4) * 4;
#pragma unroll
  for (int p = 0; p < 2; ++p) {
#pragma unroll
    for (int n = 0; n < 8; ++n)
#pragma unroll
      for (int r = 0; r < 4; ++r) {
        const int lrow = rsub + r;
        const int col = wid * 128 + n * 16 + arow;
        ldsT[lrow * 1024 + (col ^ (((lrow >> 2) & 3) << 3))] = acc[p][n][r];
      }
    __syncthreads();
#pragma unroll
    for (int q = 0; q < 2; ++q) {
      const int lr = wid * 2 + q;          // one wave -> 2 rows per pass
      const size_t grow = (size_t)(row0 + p * 16 + lr);
      const int cmask = ((lr >> 2) & 3) << 3;
      const float xq = xsq[p * 16 + lr];
      float4v dd[4];
      float dmin = 1e30f;
#pragma unroll
      for (int j = 0; j < 4; ++j) {
        const int f = lane * 4 + j * 256;
        float4v raw = *(const float4v*)&ldsT[lr * 1024 + (f ^ cmask)];
        float4v cq = *(const float4v*)(csq + f);
#pragma unroll
        for (int i = 0; i < 4; ++i) {
          float d = fmaxf(xq + cq[i] - 2.0f * raw[i], 0.0f);
          dd[j][i] = d;
          dmin = fminf(dmin, d);
        }
      }
#pragma unroll
      for (int m = 1; m < 64; m <<= 1) dmin = fminf(dmin, __shfl_xor(dmin, m));
#pragma unroll
      for (int j = 0; j < 4; ++j)
        *(float4v*)(dist + grow * NC + lane * 4 + j * 256) = dd[j];
      float ssum = 0.f;
#pragma unroll
      for (int j = 0; j < 4; ++j)
#pragma unroll
        for (int i = 0; i < 4; ++i) {
          float e = __expf(dmin - dd[j][i]);
          dd[j][i] = e;
          ssum += e;
        }
#pragma unroll
      for (int m = 1; m < 64; m <<= 1) ssum += __shfl_xor(ssum, m);
      const float sinv = 1.0f / ssum;
#pragma unroll
      for (int j = 0; j < 4; ++j) {
        float4v pv;
#pragma unroll
        for (int i = 0; i < 4; ++i) pv[i] = dd[j][i] * sinv;
        *(float4v*)(prob + grow * NC + lane * 4 + j * 256) = pv;
      }
    }
    __syncthreads();
  }
}

extern "C" void kernel_launch(void* const* d_in, const int* in_sizes, int n_in,
                              void* d_out, int out_size, void* d_ws, size_t ws_size,
                              hipStream_t stream) {
  const float* x = (const float*)d_in[0];
  const float* centers = (const float*)d_in[1];
  float* dist = (float*)d_out;
  float* prob = dist + (size_t)NROWS * NC;

  uint16_t* cs_hi = (uint16_t*)d_ws;                 // 1 MB
  uint16_t* cs_lo = cs_hi + (size_t)NC * ND;         // 1 MB
  float* csq = (float*)(cs_lo + (size_t)NC * ND);    // 4 KB

  prep_centers<<<dim3(NC), dim3(64), 0, stream>>>(centers, cs_hi, cs_lo, csq);
  kmeans_fused<<<dim3(NROWS / BM), dim3(512), 0, stream>>>(x, cs_hi, cs_lo, csq,
                                                           dist, prob);
}